// Round 6
// baseline (172.792 us; speedup 1.0000x reference)
//
#include <hip/hip_runtime.h>
#include <math.h>

// Problem constants (from reference)
constexpr int IC   = 8;    // in channels
constexpr int OC   = 32;   // out channels
constexpr int KS   = 5;    // kernel size
constexpr int B_   = 16;   // batch
constexpr int HW_  = 128;  // H = W
constexpr int FH   = 124;  // output spatial (H - KS + 1)
constexpr int KTAP = KS * KS; // 25
constexpr int OG   = 4;    // output-channel groups (blockIdx.z)
constexpr int OPG  = 8;    // output channels per group

typedef _Float16 h2 __attribute__((ext_vector_type(2)));

// ---------------------------------------------------------------------------
// Pack -K_hit / -K_miss into f16x2 broadcast pairs.
// Layout: Kpk[((c*OG+g)*KTAP + t)*16 + h*8 + oi], h=0 hit, h=1 miss.
// For fixed (c,g,t) the 16 dwords are contiguous -> wide s_load batches.
__global__ void pack_k_kernel(const float* __restrict__ Kh,
                              const float* __restrict__ Km,
                              unsigned* __restrict__ Kpk) {
    int idx = blockIdx.x * 256 + threadIdx.x;
    if (idx >= IC * OG * KTAP * 2 * OPG) return;   // 12800 dwords
    int oi = idx & 7;
    int h  = (idx >> 3) & 1;
    int t  = (idx >> 4) % KTAP;
    int cg = (idx >> 4) / KTAP;
    int g  = cg & (OG - 1), c = cg >> 2;
    int o  = g * OPG + oi;
    const float* K = h ? Km : Kh;
    float k = -K[(o * IC + c) * KTAP + t];
    _Float16 nk = (_Float16)k;
    unsigned short us = __builtin_bit_cast(unsigned short, nk);
    Kpk[idx] = (unsigned)us | ((unsigned)us << 16);
}

// ---------------------------------------------------------------------------
// Packed-f16 hit-or-miss, TWO output rows per lane (i0, i0+1).
// Each K dword (read once via wave-uniform s_load) feeds 4 VALU ops
// (2 rows x add+min) -> K scalar-stream stall share halves vs 1-row version.
// Lane = 2 adjacent output pixels; 8 output channels (g = blockIdx.z).
__global__ __launch_bounds__(256, 4) void hitmiss_f16_kernel(
    const float* __restrict__ x,
    const unsigned* __restrict__ Kpk,
    float* __restrict__ out)
{
    const int lane = threadIdx.x & 63;
    const int wid  = threadIdx.x >> 6;
    const int i0 = blockIdx.x * 8 + wid * 2;   // this wave: rows i0, i0+1
    const int b = blockIdx.y, g = blockIdx.z;
    const int j0 = lane * 2;
    if (j0 >= FH || i0 >= FH) return;   // tail waves/lanes exit whole

    h2 hit[2][OPG], miss[2][OPG];
    const h2 pinf = {(_Float16)INFINITY, (_Float16)INFINITY};
    const h2 ninf = {(_Float16)(-INFINITY), (_Float16)(-INFINITY)};
#pragma unroll
    for (int r = 0; r < 2; ++r)
#pragma unroll
        for (int oi = 0; oi < OPG; ++oi) { hit[r][oi] = pinf; miss[r][oi] = ninf; }

#pragma unroll 1   // keep c rolled: per-c body ~14KB, fits I-cache
    for (int c = 0; c < IC; ++c) {
        const float* xp = x + (((b * IC + c) * HW_) + i0) * HW_ + j0;
        // xq[r][v] = f16x2(x[i0+r][j0+v], x[i0+r][j0+1+v]), r=0..5, v=0..4
        h2 xq[KS + 1][KS];
#pragma unroll
        for (int r = 0; r < KS + 1; ++r) {
            const float2 f0 = *(const float2*)(xp + r * HW_);
            const float2 f1 = *(const float2*)(xp + r * HW_ + 2);
            const float2 f2 = *(const float2*)(xp + r * HW_ + 4);
            const float fv[6] = {f0.x, f0.y, f1.x, f1.y, f2.x, f2.y};
#pragma unroll
            for (int v = 0; v < KS; ++v)
                xq[r][v] = __builtin_bit_cast(h2,
                    __builtin_amdgcn_cvt_pkrtz(fv[v], fv[v + 1]));
        }
        const unsigned* kc = Kpk + (size_t)((c * OG + g) * KTAP) * 2 * OPG;
#pragma unroll
        for (int u = 0; u < KS; ++u) {
#pragma unroll
            for (int v = 0; v < KS; ++v) {
                const int t = u * KS + v;
#pragma unroll
                for (int oi = 0; oi < OPG; ++oi) {
                    const h2 nh = __builtin_bit_cast(h2, kc[t * 16 + oi]);
                    const h2 nm = __builtin_bit_cast(h2, kc[t * 16 + 8 + oi]);
                    hit[0][oi]  = __builtin_elementwise_min(xq[u][v]     + nh, hit[0][oi]);
                    hit[1][oi]  = __builtin_elementwise_min(xq[u + 1][v] + nh, hit[1][oi]);
                    miss[0][oi] = __builtin_elementwise_max(xq[u][v]     + nm, miss[0][oi]);
                    miss[1][oi] = __builtin_elementwise_max(xq[u + 1][v] + nm, miss[1][oi]);
                }
            }
        }
    }

#pragma unroll
    for (int r = 0; r < 2; ++r)
#pragma unroll
    for (int oi = 0; oi < OPG; ++oi) {
        const h2 res = hit[r][oi] - miss[r][oi];
        const int o = g * OPG + oi;
        float* op = out + (((size_t)b * OC + o) * FH + (i0 + r)) * FH + j0;
        float2 st; st.x = (float)res[0]; st.y = (float)res[1];
        *(float2*)op = st;   // 8B aligned: row base even, j0 even
    }
}

// ---------------------------------------------------------------------------
// f32 fallback (K in original (O,C,5,5) layout) — only used if d_ws is too
// small for the packed K table.
__global__ __launch_bounds__(128) void hitmiss_f32_kernel(
    const float* __restrict__ x,
    const float* __restrict__ Kh,
    const float* __restrict__ Km,
    float* __restrict__ out)
{
    const int j = threadIdx.x;
    const int i = blockIdx.x;
    const int b = blockIdx.y;
    if (j >= FH) return;

    float hit[OC], miss[OC];
#pragma unroll
    for (int o = 0; o < OC; ++o) { hit[o] = INFINITY; miss[o] = -INFINITY; }

#pragma unroll 1
    for (int c = 0; c < IC; ++c) {
        const float* xp = x + (((b * IC + c) * HW_) + i) * HW_ + j;
        float xw[KTAP];
#pragma unroll
        for (int u = 0; u < KS; ++u)
#pragma unroll
            for (int v = 0; v < KS; ++v)
                xw[u * KS + v] = xp[u * HW_ + v];
#pragma unroll
        for (int t = 0; t < KTAP - 1; t += 2) {
            const float x0 = xw[t], x1 = xw[t + 1];
#pragma unroll
            for (int o = 0; o < OC; ++o) {
                const float kh0 = Kh[(o * IC + c) * KTAP + t];
                const float kh1 = Kh[(o * IC + c) * KTAP + t + 1];
                const float km0 = Km[(o * IC + c) * KTAP + t];
                const float km1 = Km[(o * IC + c) * KTAP + t + 1];
                hit[o]  = fminf(fminf(x0 - kh0, x1 - kh1), hit[o]);
                miss[o] = fmaxf(fmaxf(x0 - km0, x1 - km1), miss[o]);
            }
        }
        {
            const float x0 = xw[KTAP - 1];
#pragma unroll
            for (int o = 0; o < OC; ++o) {
                hit[o]  = fminf(hit[o],  x0 - Kh[(o * IC + c) * KTAP + KTAP - 1]);
                miss[o] = fmaxf(miss[o], x0 - Km[(o * IC + c) * KTAP + KTAP - 1]);
            }
        }
    }

    float* op = out + ((size_t)(b * OC) * FH + i) * FH + j;
#pragma unroll
    for (int o = 0; o < OC; ++o)
        op[(size_t)o * FH * FH] = hit[o] - miss[o];
}

extern "C" void kernel_launch(void* const* d_in, const int* in_sizes, int n_in,
                              void* d_out, int out_size, void* d_ws, size_t ws_size,
                              hipStream_t stream) {
    const float* x  = (const float*)d_in[0];
    const float* Kh = (const float*)d_in[1];
    const float* Km = (const float*)d_in[2];
    float* out = (float*)d_out;

    const size_t kdwords = (size_t)IC * OG * KTAP * 2 * OPG; // 12800 dwords = 51.2 KB
    if (ws_size >= kdwords * sizeof(unsigned)) {
        unsigned* Kpk = (unsigned*)d_ws;
        pack_k_kernel<<<(int)((kdwords + 255) / 256), 256, 0, stream>>>(Kh, Km, Kpk);
        // block = 4 waves; wave w covers output rows (bx*8 + 2w, +1).
        // grid.x = 16 covers rows 0..127; tail waves exit on i0 >= 124.
        dim3 grid(16, B_, OG);
        hitmiss_f16_kernel<<<grid, 256, 0, stream>>>(x, Kpk, out);
    } else {
        dim3 grid(FH, B_);
        hitmiss_f32_kernel<<<grid, 128, 0, stream>>>(x, Kh, Km, out);
    }
}

// Round 7
// 171.347 us; speedup vs baseline: 1.0084x; 1.0084x over previous
//
#include <hip/hip_runtime.h>
#include <math.h>

// Problem constants (from reference)
constexpr int IC   = 8;    // in channels
constexpr int OC   = 32;   // out channels
constexpr int KS   = 5;    // kernel size
constexpr int B_   = 16;   // batch
constexpr int HW_  = 128;  // H = W
constexpr int FH   = 124;  // output spatial (H - KS + 1)
constexpr int KTAP = KS * KS; // 25
constexpr int OG   = 4;    // output-channel groups (blockIdx.z)
constexpr int OPG  = 8;    // output channels per group
constexpr int RPW  = 4;    // output rows per wave (124 = 4*31)

typedef _Float16 h2 __attribute__((ext_vector_type(2)));

// ---------------------------------------------------------------------------
// Pack -K_hit / -K_miss into f16x2 broadcast pairs.
// Layout: Kpk[((c*OG+g)*KTAP + t)*16 + h*8 + oi], h=0 hit, h=1 miss.
// For fixed (c,g,t) the 16 dwords are contiguous -> wide s_load batches.
__global__ void pack_k_kernel(const float* __restrict__ Kh,
                              const float* __restrict__ Km,
                              unsigned* __restrict__ Kpk) {
    int idx = blockIdx.x * 256 + threadIdx.x;
    if (idx >= IC * OG * KTAP * 2 * OPG) return;   // 12800 dwords
    int oi = idx & 7;
    int h  = (idx >> 3) & 1;
    int t  = (idx >> 4) % KTAP;
    int cg = (idx >> 4) / KTAP;
    int g  = cg & (OG - 1), c = cg >> 2;
    int o  = g * OPG + oi;
    const float* K = h ? Km : Kh;
    float k = -K[(o * IC + c) * KTAP + t];
    _Float16 nk = (_Float16)k;
    unsigned short us = __builtin_bit_cast(unsigned short, nk);
    Kpk[idx] = (unsigned)us | ((unsigned)us << 16);
}

// ---------------------------------------------------------------------------
// Packed-f16 hit-or-miss, FOUR output rows per lane (i0..i0+3).
// Each K dword (wave-uniform s_load, zero VALU-issue cost) now feeds 8 VALU
// ops (4 rows x add+minmax) -> SMEM-stream-per-VALU halves vs the 2-row
// version. Lane = 2 adjacent output pixels; 8 channels (g = blockIdx.z).
__global__ __launch_bounds__(128, 2) void hitmiss_f16_kernel(
    const float* __restrict__ x,
    const unsigned* __restrict__ Kpk,
    float* __restrict__ out)
{
    const int lane = threadIdx.x & 63;
    const int wid  = threadIdx.x >> 6;
    const int i0 = blockIdx.x * (2 * RPW) + wid * RPW;  // rows i0..i0+3
    const int b = blockIdx.y, g = blockIdx.z;
    const int j0 = lane * 2;
    if (j0 >= FH || i0 >= FH) return;   // tail waves/lanes exit whole

    h2 hit[RPW][OPG], miss[RPW][OPG];
    const h2 pinf = {(_Float16)INFINITY, (_Float16)INFINITY};
    const h2 ninf = {(_Float16)(-INFINITY), (_Float16)(-INFINITY)};
#pragma unroll
    for (int r = 0; r < RPW; ++r)
#pragma unroll
        for (int oi = 0; oi < OPG; ++oi) { hit[r][oi] = pinf; miss[r][oi] = ninf; }

#pragma unroll 1   // keep c rolled: hot body ~26KB, fits 32KB L1I
    for (int c = 0; c < IC; ++c) {
        const float* xp = x + (((b * IC + c) * HW_) + i0) * HW_ + j0;
        // xq[r][v] = f16x2(x[i0+r][j0+v], x[i0+r][j0+1+v]), r=0..7, v=0..4
        h2 xq[RPW + KS - 1][KS];
#pragma unroll
        for (int r = 0; r < RPW + KS - 1; ++r) {
            const float2 f0 = *(const float2*)(xp + r * HW_);
            const float2 f1 = *(const float2*)(xp + r * HW_ + 2);
            const float2 f2 = *(const float2*)(xp + r * HW_ + 4);
            const float fv[6] = {f0.x, f0.y, f1.x, f1.y, f2.x, f2.y};
#pragma unroll
            for (int v = 0; v < KS; ++v)
                xq[r][v] = __builtin_bit_cast(h2,
                    __builtin_amdgcn_cvt_pkrtz(fv[v], fv[v + 1]));
        }
        const unsigned* kc = Kpk + (size_t)((c * OG + g) * KTAP) * 2 * OPG;
#pragma unroll
        for (int u = 0; u < KS; ++u) {
#pragma unroll
            for (int v = 0; v < KS; ++v) {
                const int t = u * KS + v;
#pragma unroll
                for (int oi = 0; oi < OPG; ++oi) {
                    const h2 nh = __builtin_bit_cast(h2, kc[t * 16 + oi]);
                    const h2 nm = __builtin_bit_cast(h2, kc[t * 16 + 8 + oi]);
#pragma unroll
                    for (int r = 0; r < RPW; ++r) {
                        hit[r][oi]  = __builtin_elementwise_min(xq[u + r][v] + nh, hit[r][oi]);
                        miss[r][oi] = __builtin_elementwise_max(xq[u + r][v] + nm, miss[r][oi]);
                    }
                }
            }
        }
    }

#pragma unroll
    for (int r = 0; r < RPW; ++r)
#pragma unroll
    for (int oi = 0; oi < OPG; ++oi) {
        const h2 res = hit[r][oi] - miss[r][oi];
        const int o = g * OPG + oi;
        float* op = out + (((size_t)b * OC + o) * FH + (i0 + r)) * FH + j0;
        float2 st; st.x = (float)res[0]; st.y = (float)res[1];
        *(float2*)op = st;   // 8B aligned: row stride even, j0 even
    }
}

// ---------------------------------------------------------------------------
// f32 fallback (K in original (O,C,5,5) layout) — only used if d_ws is too
// small for the packed K table.
__global__ __launch_bounds__(128) void hitmiss_f32_kernel(
    const float* __restrict__ x,
    const float* __restrict__ Kh,
    const float* __restrict__ Km,
    float* __restrict__ out)
{
    const int j = threadIdx.x;
    const int i = blockIdx.x;
    const int b = blockIdx.y;
    if (j >= FH) return;

    float hit[OC], miss[OC];
#pragma unroll
    for (int o = 0; o < OC; ++o) { hit[o] = INFINITY; miss[o] = -INFINITY; }

#pragma unroll 1
    for (int c = 0; c < IC; ++c) {
        const float* xp = x + (((b * IC + c) * HW_) + i) * HW_ + j;
        float xw[KTAP];
#pragma unroll
        for (int u = 0; u < KS; ++u)
#pragma unroll
            for (int v = 0; v < KS; ++v)
                xw[u * KS + v] = xp[u * HW_ + v];
#pragma unroll
        for (int t = 0; t < KTAP - 1; t += 2) {
            const float x0 = xw[t], x1 = xw[t + 1];
#pragma unroll
            for (int o = 0; o < OC; ++o) {
                const float kh0 = Kh[(o * IC + c) * KTAP + t];
                const float kh1 = Kh[(o * IC + c) * KTAP + t + 1];
                const float km0 = Km[(o * IC + c) * KTAP + t];
                const float km1 = Km[(o * IC + c) * KTAP + t + 1];
                hit[o]  = fminf(fminf(x0 - kh0, x1 - kh1), hit[o]);
                miss[o] = fmaxf(fmaxf(x0 - km0, x1 - km1), miss[o]);
            }
        }
        {
            const float x0 = xw[KTAP - 1];
#pragma unroll
            for (int o = 0; o < OC; ++o) {
                hit[o]  = fminf(hit[o],  x0 - Kh[(o * IC + c) * KTAP + KTAP - 1]);
                miss[o] = fmaxf(miss[o], x0 - Km[(o * IC + c) * KTAP + KTAP - 1]);
            }
        }
    }

    float* op = out + ((size_t)(b * OC) * FH + i) * FH + j;
#pragma unroll
    for (int o = 0; o < OC; ++o)
        op[(size_t)o * FH * FH] = hit[o] - miss[o];
}

extern "C" void kernel_launch(void* const* d_in, const int* in_sizes, int n_in,
                              void* d_out, int out_size, void* d_ws, size_t ws_size,
                              hipStream_t stream) {
    const float* x  = (const float*)d_in[0];
    const float* Kh = (const float*)d_in[1];
    const float* Km = (const float*)d_in[2];
    float* out = (float*)d_out;

    const size_t kdwords = (size_t)IC * OG * KTAP * 2 * OPG; // 12800 dwords = 51.2 KB
    if (ws_size >= kdwords * sizeof(unsigned)) {
        unsigned* Kpk = (unsigned*)d_ws;
        pack_k_kernel<<<(int)((kdwords + 255) / 256), 256, 0, stream>>>(Kh, Km, Kpk);
        // block = 2 waves; wave w covers rows bx*8 + w*4 .. +3.
        // grid.x = 16 -> i0 in {0,4,...,120}; i0 = 124 exits (tail).
        dim3 grid(16, B_, OG);
        hitmiss_f16_kernel<<<grid, 128, 0, stream>>>(x, Kpk, out);
    } else {
        dim3 grid(FH, B_);
        hitmiss_f32_kernel<<<grid, 128, 0, stream>>>(x, Kh, Km, out);
    }
}